// Round 8
// baseline (1081.626 us; speedup 1.0000x reference)
//
#include <hip/hip_runtime.h>

#define T_LEN 512

typedef _Float16 h2_t  __attribute__((ext_vector_type(2)));
typedef _Float16 f16x8 __attribute__((ext_vector_type(8)));
typedef float    f32x4 __attribute__((ext_vector_type(4)));

__device__ __forceinline__ float sigf(float x) {
    return 1.0f / (1.0f + __expf(-x));
}
__device__ __forceinline__ float tanhf_(float x) {
    return 2.0f / (1.0f + __expf(-2.0f * x)) - 1.0f;
}
__device__ __forceinline__ unsigned pack2(float x, float y) {
    h2_t p; p[0] = (_Float16)x; p[1] = (_Float16)y;
    return __builtin_bit_cast(unsigned, p);
}
__device__ __forceinline__ f32x4 c4(float4 v) {
    f32x4 r; r[0] = v.x; r[1] = v.y; r[2] = v.z; r[3] = v.w; return r;
}

// Raw barrier: waits LDS ops only (lgkmcnt), leaves global loads in flight.
__device__ __forceinline__ void lds_barrier() {
    asm volatile("s_waitcnt lgkmcnt(0)" ::: "memory");
    __builtin_amdgcn_s_barrier();
    asm volatile("" ::: "memory");
}

// ---------------- Prep: Wt1[col 0..511][k 0..319] f16 (x-part, col>=256 -> w1b) --
__global__ __launch_bounds__(64) void prep_w1(
    const float* __restrict__ w1f, const float* __restrict__ w1b,
    _Float16* __restrict__ Wt1)
{
    const int col = blockIdx.x;
    const int t   = threadIdx.x;
    if (t >= 40) return;
    const float* __restrict__ W = (col < 256) ? w1f : w1b;
    const int c = col & 255;
    f16x8 v;
    #pragma unroll
    for (int i = 0; i < 8; ++i) {
        int k = t * 8 + i;
        float x = (k < 300) ? W[(size_t)k * 256 + c] : 0.0f;
        v[i] = (_Float16)x;
    }
    *(f16x8*)(Wt1 + (size_t)col * 320 + t * 8) = v;
}

// ---------------- Prep: Wt2[col 0..255][k 0..127] f16 (x-part, col>=128 -> w2b) --
__global__ __launch_bounds__(64) void prep_w2(
    const float* __restrict__ w2f, const float* __restrict__ w2b,
    _Float16* __restrict__ Wt2)
{
    const int col = blockIdx.x;
    const int t   = threadIdx.x;
    if (t >= 16) return;
    const float* __restrict__ W = (col < 128) ? w2f : w2b;
    const int c = col & 127;
    f16x8 v;
    #pragma unroll
    for (int i = 0; i < 8; ++i) {
        int k = t * 8 + i;
        v[i] = (_Float16)W[(size_t)k * 128 + c];
    }
    *(f16x8*)(Wt2 + (size_t)col * 128 + t * 8) = v;
}

// ---------------- Prep: Whr1[dir*256 + col'][k 0..63] f16, col' = u*4+g ----------
__global__ __launch_bounds__(64) void prep_whr1(
    const float* __restrict__ w1f, const float* __restrict__ w1b,
    _Float16* __restrict__ Whr1)
{
    const int x    = blockIdx.x;          // 0..511
    const int dir  = x >> 8, colp = x & 255;
    const int u = colp >> 2, g = colp & 3;
    const int k = threadIdx.x;            // 0..63
    const float* __restrict__ W = dir ? w1b : w1f;
    Whr1[(size_t)x * 64 + k] = (_Float16)W[(size_t)(300 + k) * 256 + g * 64 + u];
}

// ---------------- Prep: Whr2[dir*128 + col''][k 0..31] f16, col'' = u*4+g --------
__global__ __launch_bounds__(64) void prep_whr2(
    const float* __restrict__ w2f, const float* __restrict__ w2b,
    _Float16* __restrict__ Whr2)
{
    const int x    = blockIdx.x;          // 0..255
    const int dir  = x >> 7, colp = x & 127;
    const int u = colp >> 2, g = colp & 3;
    const int k = threadIdx.x;
    if (k >= 32) return;
    const float* __restrict__ W = dir ? w2b : w2f;
    Whr2[(size_t)x * 32 + k] = (_Float16)W[(size_t)(128 + k) * 128 + g * 32 + u];
}

// ---------------- GEMM1 (MFMA f16): Z1p = gather(emb,tok) @ Wx1 + b1 ------------
// Z1p layout: [(dir*4+bg)*512 + t][b16][col'=u*4+g] f32 (lane-local float4 in lstm1)
__global__ __launch_bounds__(256, 1) void gemm1_kernel(
    const int* __restrict__ tok, const float* __restrict__ emb,
    const _Float16* __restrict__ Wt1,
    const float* __restrict__ b1f, const float* __restrict__ b1b,
    float* __restrict__ Z1p)
{
    const int row0 = blockIdx.x * 64;            // flat row = b*512 + t
    const int b    = row0 >> 9;
    const int t0   = row0 & 511;
    const int tid  = threadIdx.x;

    __shared__ __align__(16) _Float16 A_lds[64][328];

    {
        const int row = tid >> 2, q = tid & 3;
        const int tk = tok[b * T_LEN + t0 + row];
        const float* __restrict__ src = emb + (size_t)tk * 300 + q * 80;
        #pragma unroll
        for (int i = 0; i < 20; ++i) {
            float4 v;
            if (q == 3 && i >= 15) v = make_float4(0.f, 0.f, 0.f, 0.f);
            else                   v = *(const float4*)(src + i * 4);
            uint2 u; u.x = pack2(v.x, v.y); u.y = pack2(v.z, v.w);
            *(uint2*)&A_lds[row][q * 80 + i * 4] = u;
        }
    }
    __syncthreads();

    const int l   = tid & 63;
    const int w   = tid >> 6;
    const int wN0 = w * 128;
    const int lr  = l & 15;
    const int lk8 = (l >> 4) * 8;

    f32x4 acc[4][8] = {};

    #pragma unroll 2
    for (int ks = 0; ks < 10; ++ks) {
        const int k0 = ks * 32;
        f16x8 af[4];
        #pragma unroll
        for (int m = 0; m < 4; ++m)
            af[m] = *(const f16x8*)&A_lds[m * 16 + lr][k0 + lk8];
        f16x8 bf[8];
        #pragma unroll
        for (int n = 0; n < 8; ++n)
            bf[n] = *(const f16x8*)(Wt1 + (size_t)(wN0 + n * 16 + lr) * 320 + k0 + lk8);
        #pragma unroll
        for (int m = 0; m < 4; ++m)
            #pragma unroll
            for (int n = 0; n < 8; ++n)
                acc[m][n] = __builtin_amdgcn_mfma_f32_16x16x32_f16(af[m], bf[n], acc[m][n], 0, 0, 0);
    }

    // epilogue: D row=(l>>4)*4+r (t offset), col=l&15 (within n-tile)
    const int dir = wN0 >> 8;
    const int bg  = b >> 4, b16 = b & 15;
    const int rq  = (l >> 4) * 4;
    float* __restrict__ zslab =
        Z1p + (((size_t)(dir * 4 + bg) * 512 + t0) * 16 + b16) * 256;
    #pragma unroll
    for (int n = 0; n < 8; ++n) {
        const int colr = (wN0 + n * 16 + lr) & 255;
        const int uu = colr & 63, gg = colr >> 6;
        const int colp = uu * 4 + gg;
        const float bv = dir ? b1b[colr] : b1f[colr];
        #pragma unroll
        for (int m = 0; m < 4; ++m)
            #pragma unroll
            for (int r = 0; r < 4; ++r)
                zslab[(size_t)(m * 16 + rq + r) * 4096 + colp] = acc[m][n][r] + bv;
    }
}

// ---------------- GEMM2 (MFMA f16): Z2p = H1f @ Wx2 + b2 ------------------------
// H1f: [b][t][128] f16. Z2p: [(dir*4+bg)*512 + t][b16][col''=u*4+g] f32
__global__ __launch_bounds__(256, 1) void gemm2_kernel(
    const _Float16* __restrict__ H1f,
    const _Float16* __restrict__ Wt2,
    const float* __restrict__ b2f, const float* __restrict__ b2b,
    float* __restrict__ Z2p)
{
    const int row0 = blockIdx.x * 64;
    const int b    = row0 >> 9;
    const int t0   = row0 & 511;
    const int tid  = threadIdx.x;

    __shared__ __align__(16) _Float16 A_lds[64][136];

    {
        const int row = tid >> 2, q = tid & 3;
        const _Float16* __restrict__ src = H1f + (size_t)(row0 + row) * 128 + q * 32;
        #pragma unroll
        for (int i = 0; i < 4; ++i)
            *(f16x8*)&A_lds[row][q * 32 + i * 8] = *(const f16x8*)(src + i * 8);
    }
    __syncthreads();

    const int l   = tid & 63;
    const int w   = tid >> 6;
    const int wN0 = w * 64;
    const int lr  = l & 15;
    const int lk8 = (l >> 4) * 8;

    f32x4 acc[4][4] = {};

    #pragma unroll
    for (int ks = 0; ks < 4; ++ks) {
        const int k0 = ks * 32;
        f16x8 af[4];
        #pragma unroll
        for (int m = 0; m < 4; ++m)
            af[m] = *(const f16x8*)&A_lds[m * 16 + lr][k0 + lk8];
        f16x8 bf[4];
        #pragma unroll
        for (int n = 0; n < 4; ++n)
            bf[n] = *(const f16x8*)(Wt2 + (size_t)(wN0 + n * 16 + lr) * 128 + k0 + lk8);
        #pragma unroll
        for (int m = 0; m < 4; ++m)
            #pragma unroll
            for (int n = 0; n < 4; ++n)
                acc[m][n] = __builtin_amdgcn_mfma_f32_16x16x32_f16(af[m], bf[n], acc[m][n], 0, 0, 0);
    }

    const int dir = wN0 >> 7;
    const int bg  = b >> 4, b16 = b & 15;
    const int rq  = (l >> 4) * 4;
    float* __restrict__ zslab =
        Z2p + (((size_t)(dir * 4 + bg) * 512 + t0) * 16 + b16) * 128;
    #pragma unroll
    for (int n = 0; n < 4; ++n) {
        const int colr = (wN0 + n * 16 + lr) & 127;
        const int uu = colr & 31, gg = colr >> 5;
        const int colp = uu * 4 + gg;
        const float bv = dir ? b2b[colr] : b2f[colr];
        #pragma unroll
        for (int m = 0; m < 4; ++m)
            #pragma unroll
            for (int r = 0; r < 4; ++r)
                zslab[(size_t)(m * 16 + rq + r) * 2048 + colp] = acc[m][n][r] + bv;
    }
}

// ---------------- LSTM layer 1 (MFMA recurrence): 16 chains per block ------------
// Block = (dir, bgroup of 16 b), 8 waves. Wave w owns tiles {2w,2w+1} of the 256
// col' (=u*4+g) gate dim. Per step: D[col'][b] = Wh'*h + Zx via 2 chained MFMA per
// tile (K=64); D frag gives all 4 gates of unit u=(tile*4+q) in one lane's f32x4:
// cell update is lane-local (no shuffles). h crosses waves via f16 LDS,
// double-buffered, one lgkm-only barrier per step. Zx prefetched 4 steps deep.
__global__ __launch_bounds__(512, 1) void lstm1_kernel(
    const float* __restrict__ Z1p,
    const _Float16* __restrict__ Whr1,
    _Float16* __restrict__ H1f)
{
    const int bg  = blockIdx.x & 3;
    const int dir = blockIdx.x >> 2;
    const int tid = threadIdx.x;
    const int w   = tid >> 6;           // 0..7
    const int l   = tid & 63;
    const int bb  = l & 15;             // batch within group (D col / B frag 16-dim)
    const int q   = l >> 4;             // quarter (k-chunk / D row group)

    // A frags: Wh'[col' = tile*16 + bb][k = ks*32 + q*8 + i]
    f16x8 af[2][2];
    #pragma unroll
    for (int tt = 0; tt < 2; ++tt) {
        const int colp = (2 * w + tt) * 16 + bb;
        #pragma unroll
        for (int ks = 0; ks < 2; ++ks)
            af[tt][ks] = *(const f16x8*)&Whr1[(size_t)(dir * 256 + colp) * 64 + ks * 32 + q * 8];
    }

    __shared__ __align__(16) _Float16 hbuf[2][16][72];   // +8 pad: 2-way banks
    for (int i = tid; i < 2 * 16 * 72; i += 512) ((_Float16*)hbuf)[i] = (_Float16)0.0f;
    lds_barrier();

    float cc0 = 0.0f, cc1 = 0.0f;

    const size_t dslab = (size_t)(dir * 4 + bg) * 512;
    const float* __restrict__ zb0 = Z1p + (dslab * 16 + bb) * 256 + (2 * w) * 16 + q * 4;
    const float* __restrict__ zb1 = zb0 + 16;

    float4 zr0[4], zr1[4];
    #pragma unroll
    for (int p = 0; p < 4; ++p) {
        int t = dir ? (T_LEN - 1 - p) : p;
        zr0[p] = *(const float4*)(zb0 + (size_t)t * 4096);
        zr1[p] = *(const float4*)(zb1 + (size_t)t * 4096);
    }

    const int u0 = 8 * w + q, u1 = u0 + 4;   // units of tiles 2w, 2w+1
    _Float16* __restrict__ hO = H1f + ((size_t)(bg * 16 + bb) * T_LEN) * 128 + dir * 64;

    for (int s = 0; s < T_LEN; ++s) {
        const int par = s & 1;
        const int t = dir ? (T_LEN - 1 - s) : s;
        f16x8 B0 = *(const f16x8*)&hbuf[par][bb][q * 8];        // h[k 0..31]
        f16x8 B1 = *(const f16x8*)&hbuf[par][bb][32 + q * 8];   // h[k 32..63]
        const int slot = s & 3;
        f32x4 acc0 = __builtin_amdgcn_mfma_f32_16x16x32_f16(af[0][0], B0, c4(zr0[slot]), 0, 0, 0);
        acc0 = __builtin_amdgcn_mfma_f32_16x16x32_f16(af[0][1], B1, acc0, 0, 0, 0);
        f32x4 acc1 = __builtin_amdgcn_mfma_f32_16x16x32_f16(af[1][0], B0, c4(zr1[slot]), 0, 0, 0);
        acc1 = __builtin_amdgcn_mfma_f32_16x16x32_f16(af[1][1], B1, acc1, 0, 0, 0);
        {   // refill ring slot for step s+4 (stays in flight across barrier)
            int sp = s + 4; if (sp > T_LEN - 1) sp = T_LEN - 1;
            int tp = dir ? (T_LEN - 1 - sp) : sp;
            zr0[slot] = *(const float4*)(zb0 + (size_t)tp * 4096);
            zr1[slot] = *(const float4*)(zb1 + (size_t)tp * 4096);
        }
        // lane-local cell updates (gates f,i,g,o = acc[0..3])
        float f0 = sigf(acc0[0]), i0 = sigf(acc0[1]), g0 = tanhf_(acc0[2]), o0 = sigf(acc0[3]);
        cc0 = fmaf(f0, cc0, i0 * g0);
        float h0 = o0 * tanhf_(cc0);
        float f1 = sigf(acc1[0]), i1 = sigf(acc1[1]), g1 = tanhf_(acc1[2]), o1 = sigf(acc1[3]);
        cc1 = fmaf(f1, cc1, i1 * g1);
        float h1 = o1 * tanhf_(cc1);
        hO[(size_t)t * 128 + u0] = (_Float16)h0;
        hO[(size_t)t * 128 + u1] = (_Float16)h1;
        hbuf[par ^ 1][bb][u0] = (_Float16)h0;
        hbuf[par ^ 1][bb][u1] = (_Float16)h1;
        lds_barrier();
    }
}

// ---------------- LSTM layer 2 (MFMA recurrence): K=32, 1 MFMA/tile/step --------
__global__ __launch_bounds__(512, 1) void lstm2_kernel(
    const float* __restrict__ Z2p,
    const _Float16* __restrict__ Whr2,
    float* __restrict__ H2)
{
    const int bg  = blockIdx.x & 3;
    const int dir = blockIdx.x >> 2;
    const int tid = threadIdx.x;
    const int w   = tid >> 6;           // 0..7 (tile)
    const int l   = tid & 63;
    const int bb  = l & 15;
    const int q   = l >> 4;

    const int colp = w * 16 + bb;
    f16x8 af = *(const f16x8*)&Whr2[(size_t)(dir * 128 + colp) * 32 + q * 8];

    __shared__ __align__(16) _Float16 hbuf[2][16][40];   // +8 pad
    for (int i = tid; i < 2 * 16 * 40; i += 512) ((_Float16*)hbuf)[i] = (_Float16)0.0f;
    lds_barrier();

    float cc = 0.0f, h = 0.0f;

    const size_t dslab = (size_t)(dir * 4 + bg) * 512;
    const float* __restrict__ zb = Z2p + (dslab * 16 + bb) * 128 + w * 16 + q * 4;

    float4 zr[4];
    #pragma unroll
    for (int p = 0; p < 4; ++p) {
        int t = dir ? (T_LEN - 1 - p) : p;
        zr[p] = *(const float4*)(zb + (size_t)t * 2048);
    }

    const int u = w * 4 + q;            // unit 0..31

    for (int s = 0; s < T_LEN; ++s) {
        const int par = s & 1;
        f16x8 B0 = *(const f16x8*)&hbuf[par][bb][q * 8];    // h[k 0..31]
        const int slot = s & 3;
        f32x4 acc = __builtin_amdgcn_mfma_f32_16x16x32_f16(af, B0, c4(zr[slot]), 0, 0, 0);
        {
            int sp = s + 4; if (sp > T_LEN - 1) sp = T_LEN - 1;
            int tp = dir ? (T_LEN - 1 - sp) : sp;
            zr[slot] = *(const float4*)(zb + (size_t)tp * 2048);
        }
        float f = sigf(acc[0]), i = sigf(acc[1]), g = tanhf_(acc[2]), o = sigf(acc[3]);
        cc = fmaf(f, cc, i * g);
        h = o * tanhf_(cc);
        hbuf[par ^ 1][bb][u] = (_Float16)h;
        lds_barrier();
    }
    H2[(size_t)(bg * 16 + bb) * 64 + dir * 32 + u] = h;
}

// ---------------- Dense head ----------------
__global__ __launch_bounds__(256) void head_kernel(
    const float* __restrict__ H2,
    const float* __restrict__ wd, const float* __restrict__ bd,
    const float* __restrict__ wo, const float* __restrict__ bo,
    float* __restrict__ out)
{
    const int tid = threadIdx.x;
    const int b = tid >> 2, qd = tid & 3;

    float hv[64];
    #pragma unroll
    for (int v = 0; v < 64; ++v) hv[v] = H2[b * 64 + v];

    float part = 0.0f;
    #pragma unroll
    for (int iq = 0; iq < 8; ++iq) {
        int i = qd * 8 + iq;
        float a = bd[i];
        #pragma unroll
        for (int v = 0; v < 64; ++v)
            a = fmaf(hv[v], wd[v * 32 + i], a);
        a = fmaxf(a, 0.0f);
        part = fmaf(a, wo[i], part);
    }

    __shared__ float ps[256];
    ps[tid] = part;
    __syncthreads();
    if (qd == 0) {
        float s = ps[tid] + ps[tid + 1] + ps[tid + 2] + ps[tid + 3];
        out[b] = sigf(s + bo[0]);
    }
}

extern "C" void kernel_launch(void* const* d_in, const int* in_sizes, int n_in,
                              void* d_out, int out_size, void* d_ws, size_t ws_size,
                              hipStream_t stream)
{
    const int*   tok = (const int*)  d_in[0];
    const float* emb = (const float*)d_in[1];
    const float* w1f = (const float*)d_in[2];
    const float* b1f = (const float*)d_in[3];
    const float* w1b = (const float*)d_in[4];
    const float* b1b = (const float*)d_in[5];
    const float* w2f = (const float*)d_in[6];
    const float* b2f = (const float*)d_in[7];
    const float* w2b = (const float*)d_in[8];
    const float* b2b = (const float*)d_in[9];
    const float* wd  = (const float*)d_in[10];
    const float* bd  = (const float*)d_in[11];
    const float* wo  = (const float*)d_in[12];
    const float* bo  = (const float*)d_in[13];
    float* out = (float*)d_out;

    // Workspace:
    //   Z1p : 16,777,216 f32 (67.1 MB)  [ (dir*4+bg)*512 + t ][16][256] permuted
    //   H1f : 4,194,304 f16 (8.4 MB)    [b][t][128]
    //   H2  : 4096 f32
    //   Wt1 : 512*320 f16; Wt2: 256*128 f16; Whr1: 512*64 f16; Whr2: 256*32 f16
    //   Z2p aliases Z1p (dead after lstm1)
    float*    Z1p  = (float*)d_ws;
    _Float16* H1f  = (_Float16*)(Z1p + (size_t)16777216);
    float*    H2   = (float*)(H1f + (size_t)4194304);
    _Float16* Wt1  = (_Float16*)(H2 + 4096);
    _Float16* Wt2  = Wt1 + (size_t)512 * 320;
    _Float16* Whr1 = Wt2 + (size_t)256 * 128;
    _Float16* Whr2 = Whr1 + (size_t)512 * 64;
    float*    Z2p  = Z1p;

    prep_w1  <<<512, 64, 0, stream>>>(w1f, w1b, Wt1);
    prep_w2  <<<256, 64, 0, stream>>>(w2f, w2b, Wt2);
    prep_whr1<<<512, 64, 0, stream>>>(w1f, w1b, Whr1);
    prep_whr2<<<256, 64, 0, stream>>>(w2f, w2b, Whr2);
    gemm1_kernel<<<512, 256, 0, stream>>>(tok, emb, Wt1, b1f, b1b, Z1p);
    lstm1_kernel<<<8, 512, 0, stream>>>(Z1p, Whr1, H1f);
    gemm2_kernel<<<512, 256, 0, stream>>>(H1f, Wt2, b2f, b2b, Z2p);
    lstm2_kernel<<<8, 512, 0, stream>>>(Z2p, Whr2, H2);
    head_kernel<<<1, 256, 0, stream>>>(H2, wd, bd, wo, bo, out);
}

// Round 9
// 367.903 us; speedup vs baseline: 2.9400x; 2.9400x over previous
//
#include <hip/hip_runtime.h>

#define T_LEN 512

typedef _Float16 h2_t  __attribute__((ext_vector_type(2)));
typedef _Float16 f16x8 __attribute__((ext_vector_type(8)));
typedef float    f32x4 __attribute__((ext_vector_type(4)));

__device__ __forceinline__ float sigf(float x) {
    return 1.0f / (1.0f + __expf(-x));
}
__device__ __forceinline__ float tanhf_(float x) {
    return 2.0f / (1.0f + __expf(-2.0f * x)) - 1.0f;
}
__device__ __forceinline__ unsigned pack2(float x, float y) {
    h2_t p; p[0] = (_Float16)x; p[1] = (_Float16)y;
    return __builtin_bit_cast(unsigned, p);
}

// DPP quad-perm lane exchange (VALU speed, ~2cy; replaces ds-routed shfl_xor).
// 0xB1 = quad_perm [1,0,3,2] (xor1), 0x4E = quad_perm [2,3,0,1] (xor2).
__device__ __forceinline__ float dpp_xor1(float x) {
    int i = __builtin_bit_cast(int, x);
    i = __builtin_amdgcn_mov_dpp(i, 0xB1, 0xF, 0xF, true);
    return __builtin_bit_cast(float, i);
}
__device__ __forceinline__ float dpp_xor2(float x) {
    int i = __builtin_bit_cast(int, x);
    i = __builtin_amdgcn_mov_dpp(i, 0x4E, 0xF, 0xF, true);
    return __builtin_bit_cast(float, i);
}

#if defined(__has_builtin)
#  if __has_builtin(__builtin_amdgcn_fdot2)
#    define FDOT2(a, b, c) __builtin_amdgcn_fdot2((a), (b), (c), false)
#  endif
#endif
#ifndef FDOT2
__device__ __forceinline__ float fdot2_fb(h2_t a, h2_t b, float c) {
    return fmaf((float)a[0], (float)b[0], fmaf((float)a[1], (float)b[1], c));
}
#  define FDOT2(a, b, c) fdot2_fb((a), (b), (c))
#endif

// Raw barrier: waits LDS ops only (lgkmcnt), leaves global loads in flight.
__device__ __forceinline__ void lds_barrier() {
    asm volatile("s_waitcnt lgkmcnt(0)" ::: "memory");
    __builtin_amdgcn_s_barrier();
    asm volatile("" ::: "memory");
}

// ---------------- Prep: Wt1[col 0..511][k 0..319] f16 (x-part, col>=256 -> w1b) --
__global__ __launch_bounds__(64) void prep_w1(
    const float* __restrict__ w1f, const float* __restrict__ w1b,
    _Float16* __restrict__ Wt1)
{
    const int col = blockIdx.x;
    const int t   = threadIdx.x;
    if (t >= 40) return;
    const float* __restrict__ W = (col < 256) ? w1f : w1b;
    const int c = col & 255;
    f16x8 v;
    #pragma unroll
    for (int i = 0; i < 8; ++i) {
        int k = t * 8 + i;
        float x = (k < 300) ? W[(size_t)k * 256 + c] : 0.0f;
        v[i] = (_Float16)x;
    }
    *(f16x8*)(Wt1 + (size_t)col * 320 + t * 8) = v;
}

// ---------------- Prep: Wt2[col 0..255][k 0..127] f16 (x-part, col>=128 -> w2b) --
__global__ __launch_bounds__(64) void prep_w2(
    const float* __restrict__ w2f, const float* __restrict__ w2b,
    _Float16* __restrict__ Wt2)
{
    const int col = blockIdx.x;
    const int t   = threadIdx.x;
    if (t >= 16) return;
    const float* __restrict__ W = (col < 128) ? w2f : w2b;
    const int c = col & 127;
    f16x8 v;
    #pragma unroll
    for (int i = 0; i < 8; ++i) {
        int k = t * 8 + i;
        v[i] = (_Float16)W[(size_t)k * 128 + c];
    }
    *(f16x8*)(Wt2 + (size_t)col * 128 + t * 8) = v;
}

// ---------------- Prep: Whr1[dir*256 + colp][k 0..63] f16, colp = u*4+g ----------
__global__ __launch_bounds__(64) void prep_whr1(
    const float* __restrict__ w1f, const float* __restrict__ w1b,
    _Float16* __restrict__ Whr1)
{
    const int x    = blockIdx.x;          // 0..511
    const int dir  = x >> 8, colp = x & 255;
    const int u = colp >> 2, g = colp & 3;
    const int k = threadIdx.x;            // 0..63
    const float* __restrict__ W = dir ? w1b : w1f;
    Whr1[(size_t)x * 64 + k] = (_Float16)W[(size_t)(300 + k) * 256 + g * 64 + u];
}

// ---------------- Prep: Whr2[dir*128 + colp][k 0..31] f16, colp = u*4+g ----------
__global__ __launch_bounds__(64) void prep_whr2(
    const float* __restrict__ w2f, const float* __restrict__ w2b,
    _Float16* __restrict__ Whr2)
{
    const int x    = blockIdx.x;          // 0..255
    const int dir  = x >> 7, colp = x & 127;
    const int u = colp >> 2, g = colp & 3;
    const int k = threadIdx.x;
    if (k >= 32) return;
    const float* __restrict__ W = dir ? w2b : w2f;
    Whr2[(size_t)x * 32 + k] = (_Float16)W[(size_t)(128 + k) * 128 + g * 32 + u];
}

// ---------------- GEMM1 (MFMA f16): Z1 = gather(emb,tok) @ Wx1 + b1 ----------
// Z1 layout: [dir*64+b][t][256] natural cols.
__global__ __launch_bounds__(256, 1) void gemm1_kernel(
    const int* __restrict__ tok, const float* __restrict__ emb,
    const _Float16* __restrict__ Wt1,
    const float* __restrict__ b1f, const float* __restrict__ b1b,
    float* __restrict__ Z1)
{
    const int row0 = blockIdx.x * 64;            // flat row = b*512 + t
    const int b    = row0 >> 9;
    const int t0   = row0 & 511;
    const int tid  = threadIdx.x;

    __shared__ __align__(16) _Float16 A_lds[64][328];

    {
        const int row = tid >> 2, q = tid & 3;
        const int tk = tok[b * T_LEN + t0 + row];
        const float* __restrict__ src = emb + (size_t)tk * 300 + q * 80;
        #pragma unroll
        for (int i = 0; i < 20; ++i) {
            float4 v;
            if (q == 3 && i >= 15) v = make_float4(0.f, 0.f, 0.f, 0.f);
            else                   v = *(const float4*)(src + i * 4);
            uint2 u; u.x = pack2(v.x, v.y); u.y = pack2(v.z, v.w);
            *(uint2*)&A_lds[row][q * 80 + i * 4] = u;
        }
    }
    __syncthreads();

    const int l   = tid & 63;
    const int w   = tid >> 6;
    const int wN0 = w * 128;
    const int lr  = l & 15;
    const int lk8 = (l >> 4) * 8;

    f32x4 acc[4][8] = {};

    #pragma unroll 2
    for (int ks = 0; ks < 10; ++ks) {
        const int k0 = ks * 32;
        f16x8 af[4];
        #pragma unroll
        for (int m = 0; m < 4; ++m)
            af[m] = *(const f16x8*)&A_lds[m * 16 + lr][k0 + lk8];
        f16x8 bf[8];
        #pragma unroll
        for (int n = 0; n < 8; ++n)
            bf[n] = *(const f16x8*)(Wt1 + (size_t)(wN0 + n * 16 + lr) * 320 + k0 + lk8);
        #pragma unroll
        for (int m = 0; m < 4; ++m)
            #pragma unroll
            for (int n = 0; n < 8; ++n)
                acc[m][n] = __builtin_amdgcn_mfma_f32_16x16x32_f16(af[m], bf[n], acc[m][n], 0, 0, 0);
    }

    const int dir = wN0 >> 8;
    const int rq  = (l >> 4) * 4;
    #pragma unroll
    for (int n = 0; n < 8; ++n) {
        const int colr = (wN0 + n * 16 + lr) & 255;
        const float bv = dir ? b1b[colr] : b1f[colr];
        #pragma unroll
        for (int m = 0; m < 4; ++m) {
            const size_t rb = (size_t)dir * 32768 + row0 + m * 16 + rq;
            #pragma unroll
            for (int r = 0; r < 4; ++r)
                Z1[(rb + r) * 256 + colr] = acc[m][n][r] + bv;
        }
    }
}

// ---------------- GEMM2 (MFMA f16): Z2 = H1f @ Wx2 + b2 ----------------
// H1f: [b][t][128] f16. Z2: [dir*64+b][t][128] natural cols.
__global__ __launch_bounds__(256, 1) void gemm2_kernel(
    const _Float16* __restrict__ H1f,
    const _Float16* __restrict__ Wt2,
    const float* __restrict__ b2f, const float* __restrict__ b2b,
    float* __restrict__ Z2)
{
    const int row0 = blockIdx.x * 64;
    const int tid  = threadIdx.x;

    __shared__ __align__(16) _Float16 A_lds[64][136];

    {
        const int row = tid >> 2, q = tid & 3;
        const _Float16* __restrict__ src = H1f + (size_t)(row0 + row) * 128 + q * 32;
        #pragma unroll
        for (int i = 0; i < 4; ++i)
            *(f16x8*)&A_lds[row][q * 32 + i * 8] = *(const f16x8*)(src + i * 8);
    }
    __syncthreads();

    const int l   = tid & 63;
    const int w   = tid >> 6;
    const int wN0 = w * 64;
    const int lr  = l & 15;
    const int lk8 = (l >> 4) * 8;

    f32x4 acc[4][4] = {};

    #pragma unroll
    for (int ks = 0; ks < 4; ++ks) {
        const int k0 = ks * 32;
        f16x8 af[4];
        #pragma unroll
        for (int m = 0; m < 4; ++m)
            af[m] = *(const f16x8*)&A_lds[m * 16 + lr][k0 + lk8];
        f16x8 bf[4];
        #pragma unroll
        for (int n = 0; n < 4; ++n)
            bf[n] = *(const f16x8*)(Wt2 + (size_t)(wN0 + n * 16 + lr) * 128 + k0 + lk8);
        #pragma unroll
        for (int m = 0; m < 4; ++m)
            #pragma unroll
            for (int n = 0; n < 4; ++n)
                acc[m][n] = __builtin_amdgcn_mfma_f32_16x16x32_f16(af[m], bf[n], acc[m][n], 0, 0, 0);
    }

    const int dir = wN0 >> 7;
    const int rq  = (l >> 4) * 4;
    #pragma unroll
    for (int n = 0; n < 4; ++n) {
        const int colr = (wN0 + n * 16 + lr) & 127;
        const float bv = dir ? b2b[colr] : b2f[colr];
        #pragma unroll
        for (int m = 0; m < 4; ++m) {
            const size_t rb = (size_t)dir * 32768 + row0 + m * 16 + rq;
            #pragma unroll
            for (int r = 0; r < 4; ++r)
                Z2[(rb + r) * 128 + colr] = acc[m][n][r] + bv;
        }
    }
}

// ---------------- LSTM layer 1: 4 waves per chain, quad-gate lanes ----------
// Block = (b,dir). Lane l of wave w: unit u=w*16+(l>>2), gate g=l&3, column
// col=g*64+u. The 4 gates of a unit live in one 4-lane quad -> exchange via
// 3 DPP quad_perm ops (VALU), no DS shuffles. Weights: contiguous 128B row of
// Whr1 (32 f16-pairs, vectorized load). h crosses waves via f16 LDS,
// double-buffered, one lgkm-only barrier per step. Z ring 4 deep.
__global__ __launch_bounds__(256, 1) void lstm1_kernel(
    const float* __restrict__ Z1,
    const _Float16* __restrict__ Whr1,
    _Float16* __restrict__ H1f)
{
    const int b   = blockIdx.x & 63;
    const int dir = blockIdx.x >> 6;
    const int tid = threadIdx.x;
    const int w   = tid >> 6;
    const int l   = tid & 63;
    const int g   = l & 3;
    const int u   = w * 16 + (l >> 2);
    const int col = g * 64 + u;

    // Wh column (colp = u*4+g = w*64+l): one contiguous 128B row.
    h2_t wc[32];
    {
        const _Float16* __restrict__ wp = Whr1 + (size_t)(dir * 256 + w * 64 + l) * 64;
        #pragma unroll
        for (int r8 = 0; r8 < 8; ++r8) {
            f16x8 v = *(const f16x8*)(wp + r8 * 8);
            #pragma unroll
            for (int j = 0; j < 4; ++j) {
                h2_t p; p[0] = v[2 * j]; p[1] = v[2 * j + 1];
                wc[r8 * 4 + j] = p;
            }
        }
    }

    __shared__ __align__(16) _Float16 hbuf[2][64];
    if (tid < 64) { hbuf[0][tid] = (_Float16)0.0f; hbuf[1][tid] = (_Float16)0.0f; }
    lds_barrier();

    float c = 0.0f;

    const float* __restrict__ zcol =
        Z1 + ((size_t)(dir * 64 + b) * T_LEN) * 256 + col;

    float zr[4];
    #pragma unroll
    for (int q = 0; q < 4; ++q) {
        int t = dir ? (T_LEN - 1 - q) : q;
        zr[q] = zcol[(size_t)t * 256];
    }

    _Float16* __restrict__ hout = H1f + (size_t)b * T_LEN * 128 + dir * 64 + u;

    const bool s0b = (g & 1) != 0, s1b = (g >> 1) != 0;
    const float km  = (g == 2) ? -2.0f : -1.0f;
    const float num = (g == 2) ?  2.0f :  1.0f;
    const float off = (g == 2) ?  1.0f :  0.0f;

    for (int sb = 0; sb < T_LEN; sb += 4) {
        #pragma unroll
        for (int q = 0; q < 4; ++q) {
            const int s = sb + q;
            const uint4* hb = (const uint4*)hbuf[s & 1];
            float a0 = zr[q], a1 = 0.f, a2 = 0.f, a3 = 0.f;
            #pragma unroll
            for (int k = 0; k < 8; ++k) {
                uint4 hq = hb[k];
                h2_t p0 = __builtin_bit_cast(h2_t, hq.x);
                h2_t p1 = __builtin_bit_cast(h2_t, hq.y);
                h2_t p2 = __builtin_bit_cast(h2_t, hq.z);
                h2_t p3 = __builtin_bit_cast(h2_t, hq.w);
                a0 = FDOT2(p0, wc[4 * k + 0], a0);
                a1 = FDOT2(p1, wc[4 * k + 1], a1);
                a2 = FDOT2(p2, wc[4 * k + 2], a2);
                a3 = FDOT2(p3, wc[4 * k + 3], a3);
            }
            float zz = (a0 + a1) + (a2 + a3);

            {   // refill ring slot (stays in flight across barriers)
                int sp = s + 4; if (sp > T_LEN - 1) sp = T_LEN - 1;
                int tp = dir ? (T_LEN - 1 - sp) : sp;
                zr[q] = zcol[(size_t)tp * 256];
            }

            // own gate activation (sig for f,i,o; tanh for g)
            float e = __expf(km * zz);
            float A = num / (1.0f + e) - off;
            // quad exchange: B=xor1, C=xor2, D=xor3 (all VALU DPP)
            float B = dpp_xor1(A);
            float C = dpp_xor2(A);
            float D = dpp_xor2(B);
            float f_ = s1b ? (s0b ? D : C) : (s0b ? B : A);
            float i_ = s1b ? (s0b ? C : D) : (s0b ? A : B);
            float g_ = s1b ? (s0b ? B : A) : (s0b ? D : C);
            float o_ = s1b ? (s0b ? A : B) : (s0b ? C : D);
            c = fmaf(f_, c, i_ * g_);
            float h = o_ * tanhf_(c);
            _Float16 h16 = (_Float16)h;
            if (g == 0) {
                int t = dir ? (T_LEN - 1 - s) : s;
                hout[(size_t)t * 128] = h16;
                hbuf[(s + 1) & 1][u] = h16;
            }
            lds_barrier();
        }
    }
}

// ---------------- LSTM layer 2: 2 waves per chain, quad-gate lanes ----------
// Lane l of wave w: unit u=w*16+(l>>2) (u<32), gate g=l&3, col=g*32+u.
__global__ __launch_bounds__(128, 1) void lstm2_kernel(
    const float* __restrict__ Z2,
    const _Float16* __restrict__ Whr2,
    float* __restrict__ H2)
{
    const int b   = blockIdx.x & 63;
    const int dir = blockIdx.x >> 6;
    const int tid = threadIdx.x;
    const int w   = tid >> 6;
    const int l   = tid & 63;
    const int g   = l & 3;
    const int u   = w * 16 + (l >> 2);
    const int col = g * 32 + u;

    h2_t wc[16];
    {
        const _Float16* __restrict__ wp = Whr2 + (size_t)(dir * 128 + w * 64 + l) * 32;
        #pragma unroll
        for (int r8 = 0; r8 < 4; ++r8) {
            f16x8 v = *(const f16x8*)(wp + r8 * 8);
            #pragma unroll
            for (int j = 0; j < 4; ++j) {
                h2_t p; p[0] = v[2 * j]; p[1] = v[2 * j + 1];
                wc[r8 * 4 + j] = p;
            }
        }
    }

    __shared__ __align__(16) _Float16 hbuf[2][32];
    if (tid < 32) { hbuf[0][tid] = (_Float16)0.0f; hbuf[1][tid] = (_Float16)0.0f; }
    lds_barrier();

    float c = 0.0f, h = 0.0f;

    const float* __restrict__ zcol =
        Z2 + ((size_t)(dir * 64 + b) * T_LEN) * 128 + col;

    float zr[4];
    #pragma unroll
    for (int q = 0; q < 4; ++q) {
        int t = dir ? (T_LEN - 1 - q) : q;
        zr[q] = zcol[(size_t)t * 128];
    }

    const bool s0b = (g & 1) != 0, s1b = (g >> 1) != 0;
    const float km  = (g == 2) ? -2.0f : -1.0f;
    const float num = (g == 2) ?  2.0f :  1.0f;
    const float off = (g == 2) ?  1.0f :  0.0f;

    for (int sb = 0; sb < T_LEN; sb += 4) {
        #pragma unroll
        for (int q = 0; q < 4; ++q) {
            const int s = sb + q;
            const uint4* hb = (const uint4*)hbuf[s & 1];
            float a0 = zr[q], a1 = 0.f, a2 = 0.f, a3 = 0.f;
            #pragma unroll
            for (int k = 0; k < 4; ++k) {
                uint4 hq = hb[k];
                h2_t p0 = __builtin_bit_cast(h2_t, hq.x);
                h2_t p1 = __builtin_bit_cast(h2_t, hq.y);
                h2_t p2 = __builtin_bit_cast(h2_t, hq.z);
                h2_t p3 = __builtin_bit_cast(h2_t, hq.w);
                a0 = FDOT2(p0, wc[4 * k + 0], a0);
                a1 = FDOT2(p1, wc[4 * k + 1], a1);
                a2 = FDOT2(p2, wc[4 * k + 2], a2);
                a3 = FDOT2(p3, wc[4 * k + 3], a3);
            }
            float zz = (a0 + a1) + (a2 + a3);

            {
                int sp = s + 4; if (sp > T_LEN - 1) sp = T_LEN - 1;
                int tp = dir ? (T_LEN - 1 - sp) : sp;
                zr[q] = zcol[(size_t)tp * 128];
            }

            float e = __expf(km * zz);
            float A = num / (1.0f + e) - off;
            float B = dpp_xor1(A);
            float C = dpp_xor2(A);
            float D = dpp_xor2(B);
            float f_ = s1b ? (s0b ? D : C) : (s0b ? B : A);
            float i_ = s1b ? (s0b ? C : D) : (s0b ? A : B);
            float g_ = s1b ? (s0b ? B : A) : (s0b ? D : C);
            float o_ = s1b ? (s0b ? A : B) : (s0b ? C : D);
            c = fmaf(f_, c, i_ * g_);
            h = o_ * tanhf_(c);
            if (g == 0)
                hbuf[(s + 1) & 1][u] = (_Float16)h;
            lds_barrier();
        }
    }
    if (g == 0)
        H2[b * 64 + dir * 32 + u] = h;
}

// ---------------- Dense head ----------------
__global__ __launch_bounds__(256) void head_kernel(
    const float* __restrict__ H2,
    const float* __restrict__ wd, const float* __restrict__ bd,
    const float* __restrict__ wo, const float* __restrict__ bo,
    float* __restrict__ out)
{
    const int tid = threadIdx.x;
    const int b = tid >> 2, qd = tid & 3;

    float hv[64];
    #pragma unroll
    for (int v = 0; v < 64; ++v) hv[v] = H2[b * 64 + v];

    float part = 0.0f;
    #pragma unroll
    for (int iq = 0; iq < 8; ++iq) {
        int i = qd * 8 + iq;
        float a = bd[i];
        #pragma unroll
        for (int v = 0; v < 64; ++v)
            a = fmaf(hv[v], wd[v * 32 + i], a);
        a = fmaxf(a, 0.0f);
        part = fmaf(a, wo[i], part);
    }

    __shared__ float ps[256];
    ps[tid] = part;
    __syncthreads();
    if (qd == 0) {
        float s = ps[tid] + ps[tid + 1] + ps[tid + 2] + ps[tid + 3];
        out[b] = sigf(s + bo[0]);
    }
}

extern "C" void kernel_launch(void* const* d_in, const int* in_sizes, int n_in,
                              void* d_out, int out_size, void* d_ws, size_t ws_size,
                              hipStream_t stream)
{
    const int*   tok = (const int*)  d_in[0];
    const float* emb = (const float*)d_in[1];
    const float* w1f = (const float*)d_in[2];
    const float* b1f = (const float*)d_in[3];
    const float* w1b = (const float*)d_in[4];
    const float* b1b = (const float*)d_in[5];
    const float* w2f = (const float*)d_in[6];
    const float* b2f = (const float*)d_in[7];
    const float* w2b = (const float*)d_in[8];
    const float* b2b = (const float*)d_in[9];
    const float* wd  = (const float*)d_in[10];
    const float* bd  = (const float*)d_in[11];
    const float* wo  = (const float*)d_in[12];
    const float* bo  = (const float*)d_in[13];
    float* out = (float*)d_out;

    // Workspace:
    //   Z1 : [2*64][512][256] f32 (67.1 MB), natural cols
    //   H1f: [64][512][128]  f16 (8.4 MB)
    //   H2 : 4096 f32
    //   Wt1: 512*320 f16; Wt2: 256*128 f16; Whr1: 512*64 f16; Whr2: 256*32 f16
    //   Z2 aliases Z1 (dead after lstm1): [2*64][512][128]
    float*    Z1   = (float*)d_ws;
    _Float16* H1f  = (_Float16*)(Z1 + (size_t)16777216);
    float*    H2   = (float*)(H1f + (size_t)4194304);
    _Float16* Wt1  = (_Float16*)(H2 + 4096);
    _Float16* Wt2  = Wt1 + (size_t)512 * 320;
    _Float16* Whr1 = Wt2 + (size_t)256 * 128;
    _Float16* Whr2 = Whr1 + (size_t)512 * 64;
    float*    Z2   = Z1;

    prep_w1  <<<512, 64, 0, stream>>>(w1f, w1b, Wt1);
    prep_w2  <<<256, 64, 0, stream>>>(w2f, w2b, Wt2);
    prep_whr1<<<512, 64, 0, stream>>>(w1f, w1b, Whr1);
    prep_whr2<<<256, 64, 0, stream>>>(w2f, w2b, Whr2);
    gemm1_kernel<<<512, 256, 0, stream>>>(tok, emb, Wt1, b1f, b1b, Z1);
    lstm1_kernel<<<128, 256, 0, stream>>>(Z1, Whr1, H1f);
    gemm2_kernel<<<512, 256, 0, stream>>>(H1f, Wt2, b2f, b2b, Z2);
    lstm2_kernel<<<128, 128, 0, stream>>>(Z2, Whr2, H2);
    head_kernel<<<1, 256, 0, stream>>>(H2, wd, bd, wo, bo, out);
}